// Round 1
// baseline (180.261 us; speedup 1.0000x reference)
//
#include <hip/hip_runtime.h>
#include <hip/hip_bf16.h>
#include <math.h>

#define N_NODES 10000
#define N_EDGES 320000
#define IN_DIM  512
#define OUT_DIM 256
#define NEG_SLOPE 0.01f

// ---------------- GEMM: z[M][N] = h[M][K] * fc_w[N][K]^T + fc_b ----------------
#define BM 64
#define BN 64
#define BK 16

__global__ __launch_bounds__(256) void gemm_z(
    const float* __restrict__ A,   // h [M][K]
    const float* __restrict__ B,   // fc_w [N][K]
    const float* __restrict__ bias,// [N]
    float* __restrict__ C)         // z [M][N]
{
    const int M = N_NODES, N = OUT_DIM, K = IN_DIM;
    __shared__ float As[BK][BM + 4];
    __shared__ float Bs[BK][BN + 4];

    const int bm = blockIdx.x * BM;
    const int bn = blockIdx.y * BN;
    const int t  = threadIdx.x;

    // loader mapping: 4 consecutive k per thread
    const int l_row = t >> 2;        // 0..63
    const int l_k4  = (t & 3) * 4;   // 0,4,8,12

    // compute mapping
    const int r0 = (t & 15) * 4;     // row offset in tile
    const int c0 = (t >> 4) * 4;     // col offset in tile

    float acc[4][4];
#pragma unroll
    for (int i = 0; i < 4; ++i)
#pragma unroll
        for (int j = 0; j < 4; ++j) acc[i][j] = 0.f;

    for (int k0 = 0; k0 < K; k0 += BK) {
        // load A tile (guard rows)
        {
            int row = bm + l_row;
            float4 v = make_float4(0.f, 0.f, 0.f, 0.f);
            if (row < M) v = *(const float4*)&A[(size_t)row * K + k0 + l_k4];
            As[l_k4 + 0][l_row] = v.x;
            As[l_k4 + 1][l_row] = v.y;
            As[l_k4 + 2][l_row] = v.z;
            As[l_k4 + 3][l_row] = v.w;
        }
        // load B tile (N=256 exact multiple of BN, no guard)
        {
            int row = bn + l_row;
            float4 v = *(const float4*)&B[(size_t)row * K + k0 + l_k4];
            Bs[l_k4 + 0][l_row] = v.x;
            Bs[l_k4 + 1][l_row] = v.y;
            Bs[l_k4 + 2][l_row] = v.z;
            Bs[l_k4 + 3][l_row] = v.w;
        }
        __syncthreads();

#pragma unroll
        for (int k = 0; k < BK; ++k) {
            float4 a = *(const float4*)&As[k][r0];
            float4 b = *(const float4*)&Bs[k][c0];
            acc[0][0] += a.x * b.x; acc[0][1] += a.x * b.y; acc[0][2] += a.x * b.z; acc[0][3] += a.x * b.w;
            acc[1][0] += a.y * b.x; acc[1][1] += a.y * b.y; acc[1][2] += a.y * b.z; acc[1][3] += a.y * b.w;
            acc[2][0] += a.z * b.x; acc[2][1] += a.z * b.y; acc[2][2] += a.z * b.z; acc[2][3] += a.z * b.w;
            acc[3][0] += a.w * b.x; acc[3][1] += a.w * b.y; acc[3][2] += a.w * b.z; acc[3][3] += a.w * b.w;
        }
        __syncthreads();
    }

    float4 bv = *(const float4*)&bias[bn + c0];
#pragma unroll
    for (int i = 0; i < 4; ++i) {
        int r = bm + r0 + i;
        if (r < M) {
            float4 o;
            o.x = acc[i][0] + bv.x;
            o.y = acc[i][1] + bv.y;
            o.z = acc[i][2] + bv.z;
            o.w = acc[i][3] + bv.w;
            *(float4*)&C[(size_t)r * N + bn + c0] = o;
        }
    }
}

// ---------------- per-node attention dots: s_src[n]=z[n].a_src, s_dst[n]=z[n].a_dst --------
__global__ __launch_bounds__(256) void node_dots(
    const float* __restrict__ z, const float* __restrict__ attn_w,
    float* __restrict__ s_src, float* __restrict__ s_dst)
{
    const int wid = threadIdx.x >> 6;
    const int lane = threadIdx.x & 63;
    const int n = blockIdx.x * 4 + wid;
    if (n >= N_NODES) return;
    float4 zr = *(const float4*)&z[(size_t)n * OUT_DIM + lane * 4];
    float4 as = *(const float4*)&attn_w[lane * 4];
    float4 ad = *(const float4*)&attn_w[OUT_DIM + lane * 4];
    float dsv = zr.x * as.x + zr.y * as.y + zr.z * as.z + zr.w * as.w;
    float ddv = zr.x * ad.x + zr.y * ad.y + zr.z * ad.z + zr.w * ad.w;
#pragma unroll
    for (int off = 32; off; off >>= 1) {
        dsv += __shfl_down(dsv, off);
        ddv += __shfl_down(ddv, off);
    }
    if (lane == 0) { s_src[n] = dsv; s_dst[n] = ddv; }
}

// ---------------- per-edge score + dst histogram ----------------
__global__ __launch_bounds__(256) void edge_score(
    const int* __restrict__ src, const int* __restrict__ dst,
    const float* __restrict__ s_src, const float* __restrict__ s_dst,
    const float* __restrict__ attn_b,
    float* __restrict__ e_arr, int* __restrict__ deg)
{
    int k = blockIdx.x * 256 + threadIdx.x;
    if (k >= N_EDGES) return;
    float e = s_src[src[k]] + s_dst[dst[k]] + attn_b[0];
    e = (e >= 0.f) ? e : NEG_SLOPE * e;
    e_arr[k] = e;
    atomicAdd(&deg[dst[k]], 1);
}

// ---------------- single-block exclusive scan over deg -> offsets[N_NODES+1] -------------
__global__ __launch_bounds__(1024) void scan_deg(
    const int* __restrict__ deg, int* __restrict__ offsets)
{
    __shared__ int s[1024];
    const int t = threadIdx.x;
    if (t == 0) offsets[0] = 0;
    int running = 0;
    for (int base = 0; base < N_NODES; base += 1024) {
        int idx = base + t;
        int v = (idx < N_NODES) ? deg[idx] : 0;
        s[t] = v;
#pragma unroll
        for (int off = 1; off < 1024; off <<= 1) {
            __syncthreads();
            int prev = (t >= off) ? s[t - off] : 0;
            __syncthreads();
            s[t] += prev;
        }
        __syncthreads();
        if (idx < N_NODES) offsets[idx + 1] = running + s[t];
        running += s[1023];
        __syncthreads();
    }
}

// ---------------- scatter edges into CSR order ----------------
__global__ __launch_bounds__(256) void scatter_edges(
    const int* __restrict__ src, const int* __restrict__ dst,
    const float* __restrict__ e_arr, const int* __restrict__ offsets,
    int* __restrict__ cursor, int* __restrict__ src_sorted,
    float* __restrict__ e_sorted)
{
    int k = blockIdx.x * 256 + threadIdx.x;
    if (k >= N_EDGES) return;
    int d = dst[k];
    int pos = offsets[d] + atomicAdd(&cursor[d], 1);
    src_sorted[pos] = src[k];
    e_sorted[pos] = e_arr[k];
}

// ---------------- per-node softmax + weighted aggregation (one wave per node) -------------
__global__ __launch_bounds__(256) void aggregate(
    const float* __restrict__ z, const int* __restrict__ offsets,
    const int* __restrict__ src_sorted, const float* __restrict__ e_sorted,
    float* __restrict__ out)
{
    const int wid = threadIdx.x >> 6;
    const int lane = threadIdx.x & 63;
    const int n = blockIdx.x * 4 + wid;
    if (n >= N_NODES) return;
    const int beg = offsets[n], end = offsets[n + 1];

    // pass 1: max
    float m = -INFINITY;
    for (int j = beg + lane; j < end; j += 64) m = fmaxf(m, e_sorted[j]);
#pragma unroll
    for (int off = 32; off; off >>= 1) m = fmaxf(m, __shfl_down(m, off));
    m = __shfl(m, 0);

    // pass 2: denom
    float den = 0.f;
    for (int j = beg + lane; j < end; j += 64) den += expf(e_sorted[j] - m);
#pragma unroll
    for (int off = 32; off; off >>= 1) den += __shfl_down(den, off);
    den = __shfl(den, 0);
    float inv = (end > beg) ? 1.0f / den : 0.f;

    // pass 3: weighted sum of z rows
    float4 acc = make_float4(0.f, 0.f, 0.f, 0.f);
    for (int j = beg; j < end; ++j) {
        float al = expf(e_sorted[j] - m) * inv;
        float4 zr = *(const float4*)&z[(size_t)src_sorted[j] * OUT_DIM + lane * 4];
        acc.x += al * zr.x;
        acc.y += al * zr.y;
        acc.z += al * zr.z;
        acc.w += al * zr.w;
    }
    *(float4*)&out[(size_t)n * OUT_DIM + lane * 4] = acc;
}

extern "C" void kernel_launch(void* const* d_in, const int* in_sizes, int n_in,
                              void* d_out, int out_size, void* d_ws, size_t ws_size,
                              hipStream_t stream) {
    const float* h      = (const float*)d_in[0];
    const float* fc_w   = (const float*)d_in[1];
    const float* fc_b   = (const float*)d_in[2];
    const float* attn_w = (const float*)d_in[3];
    const float* attn_b = (const float*)d_in[4];
    const int*   src    = (const int*)d_in[5];
    const int*   dst    = (const int*)d_in[6];
    float* out = (float*)d_out;

    // workspace carve-up (all 16B aligned enough for float4 on z)
    float* z        = (float*)d_ws;                   // N_NODES*OUT_DIM
    float* s_src    = z + (size_t)N_NODES * OUT_DIM;  // N_NODES
    float* s_dst    = s_src + N_NODES;                // N_NODES
    float* e_arr    = s_dst + N_NODES;                // N_EDGES
    int*   deg      = (int*)(e_arr + N_EDGES);        // N_NODES
    int*   offsets  = deg + N_NODES;                  // N_NODES+1
    int*   cursor   = offsets + N_NODES + 1;          // N_NODES
    int*   src_sorted = cursor + N_NODES;             // N_EDGES
    float* e_sorted = (float*)(src_sorted + N_EDGES); // N_EDGES

    hipMemsetAsync(deg, 0, sizeof(int) * N_NODES, stream);
    hipMemsetAsync(cursor, 0, sizeof(int) * N_NODES, stream);

    dim3 ggrid((N_NODES + BM - 1) / BM, OUT_DIM / BN);
    gemm_z<<<ggrid, 256, 0, stream>>>(h, fc_w, fc_b, z);

    node_dots<<<(N_NODES + 3) / 4, 256, 0, stream>>>(z, attn_w, s_src, s_dst);

    edge_score<<<(N_EDGES + 255) / 256, 256, 0, stream>>>(src, dst, s_src, s_dst, attn_b, e_arr, deg);

    scan_deg<<<1, 1024, 0, stream>>>(deg, offsets);

    scatter_edges<<<(N_EDGES + 255) / 256, 256, 0, stream>>>(src, dst, e_arr, offsets, cursor, src_sorted, e_sorted);

    aggregate<<<(N_NODES + 3) / 4, 256, 0, stream>>>(z, offsets, src_sorted, e_sorted, out);
}

// Round 2
// 157.488 us; speedup vs baseline: 1.1446x; 1.1446x over previous
//
#include <hip/hip_runtime.h>
#include <hip/hip_bf16.h>
#include <math.h>

#define N_NODES 10000
#define N_EDGES 320000
#define IN_DIM  512
#define OUT_DIM 256
#define NEG_SLOPE 0.01f

typedef __attribute__((ext_vector_type(8))) short bf16x8;
typedef __attribute__((ext_vector_type(4))) float f32x4;

// ---------------- fp32 -> bf16 (RNE) convert, 8 elems/thread ----------------
__device__ __forceinline__ unsigned int f2bf(float x) {
    unsigned int b = __float_as_uint(x);
    return (b + 0x7fffu + ((b >> 16) & 1u)) >> 16;   // round-to-nearest-even
}

__global__ __launch_bounds__(256) void f32_to_bf16(
    const float* __restrict__ in, ushort* __restrict__ out, int n8)
{
    int i = blockIdx.x * 256 + threadIdx.x;
    if (i >= n8) return;
    const float* p = in + (size_t)i * 8;
    float4 v0 = *(const float4*)p;
    float4 v1 = *(const float4*)(p + 4);
    int4 o;
    o.x = (int)(f2bf(v0.x) | (f2bf(v0.y) << 16));
    o.y = (int)(f2bf(v0.z) | (f2bf(v0.w) << 16));
    o.z = (int)(f2bf(v1.x) | (f2bf(v1.y) << 16));
    o.w = (int)(f2bf(v1.z) | (f2bf(v1.w) << 16));
    *(int4*)(out + (size_t)i * 8) = o;
}

// ---------------- MFMA GEMM: z[M][N] = h[M][K] * fc_w[N][K]^T + fc_b --------
// block = 256 thr (4 waves), covers 16 rows x 256 cols. wave w: cols w*64..+63.
// Both operands are K-contiguous in memory -> direct 16B fragment loads, no LDS.
__global__ __launch_bounds__(256) void gemm_mfma(
    const ushort* __restrict__ A,   // h bf16 [M][K]
    const ushort* __restrict__ B,   // fc_w bf16 [N][K]
    const float* __restrict__ bias, // [N]
    float* __restrict__ C)          // z [M][N]
{
    const int K = IN_DIM;
    const int b = blockIdx.x;
    const int w = threadIdx.x >> 6;
    const int l = threadIdx.x & 63;
    const int lo = l & 15;
    const int hi = l >> 4;

    const int r0   = b * 16;        // 10000 = 625*16, exact
    const int colb = w * 64;

    const ushort* Arow = A + (size_t)(r0 + lo) * K;
    const ushort* B0 = B + (size_t)(colb + 0  + lo) * K;
    const ushort* B1 = B + (size_t)(colb + 16 + lo) * K;
    const ushort* B2 = B + (size_t)(colb + 32 + lo) * K;
    const ushort* B3 = B + (size_t)(colb + 48 + lo) * K;
    const int khalf = hi * 8;

    f32x4 acc0 = {0.f, 0.f, 0.f, 0.f};
    f32x4 acc1 = {0.f, 0.f, 0.f, 0.f};
    f32x4 acc2 = {0.f, 0.f, 0.f, 0.f};
    f32x4 acc3 = {0.f, 0.f, 0.f, 0.f};

#pragma unroll
    for (int ks = 0; ks < IN_DIM / 32; ++ks) {
        const int k = ks * 32 + khalf;
        bf16x8 a  = *(const bf16x8*)(Arow + k);
        bf16x8 b0 = *(const bf16x8*)(B0 + k);
        bf16x8 b1 = *(const bf16x8*)(B1 + k);
        bf16x8 b2 = *(const bf16x8*)(B2 + k);
        bf16x8 b3 = *(const bf16x8*)(B3 + k);
        acc0 = __builtin_amdgcn_mfma_f32_16x16x32_bf16(a, b0, acc0, 0, 0, 0);
        acc1 = __builtin_amdgcn_mfma_f32_16x16x32_bf16(a, b1, acc1, 0, 0, 0);
        acc2 = __builtin_amdgcn_mfma_f32_16x16x32_bf16(a, b2, acc2, 0, 0, 0);
        acc3 = __builtin_amdgcn_mfma_f32_16x16x32_bf16(a, b3, acc3, 0, 0, 0);
    }

    // C/D layout: col = lane&15, row = (lane>>4)*4 + i
    const float bv0 = bias[colb + 0  + lo];
    const float bv1 = bias[colb + 16 + lo];
    const float bv2 = bias[colb + 32 + lo];
    const float bv3 = bias[colb + 48 + lo];
#pragma unroll
    for (int i = 0; i < 4; ++i) {
        const int m = r0 + hi * 4 + i;
        float* cr = C + (size_t)m * OUT_DIM + colb + lo;
        cr[0]  = acc0[i] + bv0;
        cr[16] = acc1[i] + bv1;
        cr[32] = acc2[i] + bv2;
        cr[48] = acc3[i] + bv3;
    }
}

// ---------------- per-node attention dots ----------------
__global__ __launch_bounds__(256) void node_dots(
    const float* __restrict__ z, const float* __restrict__ attn_w,
    float* __restrict__ s_src, float* __restrict__ s_dst)
{
    const int wid = threadIdx.x >> 6;
    const int lane = threadIdx.x & 63;
    const int n = blockIdx.x * 4 + wid;
    if (n >= N_NODES) return;
    float4 zr = *(const float4*)&z[(size_t)n * OUT_DIM + lane * 4];
    float4 as = *(const float4*)&attn_w[lane * 4];
    float4 ad = *(const float4*)&attn_w[OUT_DIM + lane * 4];
    float dsv = zr.x * as.x + zr.y * as.y + zr.z * as.z + zr.w * as.w;
    float ddv = zr.x * ad.x + zr.y * ad.y + zr.z * ad.z + zr.w * ad.w;
#pragma unroll
    for (int off = 32; off; off >>= 1) {
        dsv += __shfl_down(dsv, off);
        ddv += __shfl_down(ddv, off);
    }
    if (lane == 0) { s_src[n] = dsv; s_dst[n] = ddv; }
}

// ---------------- per-edge score + dst histogram ----------------
__global__ __launch_bounds__(256) void edge_score(
    const int* __restrict__ src, const int* __restrict__ dst,
    const float* __restrict__ s_src, const float* __restrict__ s_dst,
    const float* __restrict__ attn_b,
    float* __restrict__ e_arr, int* __restrict__ deg)
{
    int k = blockIdx.x * 256 + threadIdx.x;
    if (k >= N_EDGES) return;
    float e = s_src[src[k]] + s_dst[dst[k]] + attn_b[0];
    e = (e >= 0.f) ? e : NEG_SLOPE * e;
    e_arr[k] = e;
    atomicAdd(&deg[dst[k]], 1);
}

// ---------------- fast single-block exclusive scan: 10 elems/thread --------
__global__ __launch_bounds__(1024) void scan_deg(
    const int* __restrict__ deg, int* __restrict__ offsets)
{
    const int t = threadIdx.x;
    const int lane = t & 63, wid = t >> 6;
    const int base = t * 10;

    int v[10];
    int tot = 0;
#pragma unroll
    for (int i = 0; i < 10; ++i) {
        int idx = base + i;
        v[i] = (idx < N_NODES) ? deg[idx] : 0;
        tot += v[i];
    }
    // wave-inclusive scan of per-thread totals
    int sc = tot;
#pragma unroll
    for (int off = 1; off < 64; off <<= 1) {
        int u = __shfl_up(sc, off);
        if (lane >= off) sc += u;
    }
    __shared__ int wsum[16];
    if (lane == 63) wsum[wid] = sc;
    __syncthreads();
    int woff = 0;
    for (int ww = 0; ww < wid; ++ww) woff += wsum[ww];

    int run = woff + sc - tot;   // exclusive prefix for this thread
    if (t == 0) offsets[0] = 0;
#pragma unroll
    for (int i = 0; i < 10; ++i) {
        int idx = base + i;
        run += v[i];
        if (idx < N_NODES) offsets[idx + 1] = run;
    }
}

// ---------------- scatter edges into CSR order ----------------
__global__ __launch_bounds__(256) void scatter_edges(
    const int* __restrict__ src, const int* __restrict__ dst,
    const float* __restrict__ e_arr, const int* __restrict__ offsets,
    int* __restrict__ cursor, int* __restrict__ src_sorted,
    float* __restrict__ e_sorted)
{
    int k = blockIdx.x * 256 + threadIdx.x;
    if (k >= N_EDGES) return;
    int d = dst[k];
    int pos = offsets[d] + atomicAdd(&cursor[d], 1);
    src_sorted[pos] = src[k];
    e_sorted[pos] = e_arr[k];
}

// ---------------- per-node softmax + weighted aggregation (wave/node) ------
__global__ __launch_bounds__(256) void aggregate(
    const float* __restrict__ z, const int* __restrict__ offsets,
    const int* __restrict__ src_sorted, const float* __restrict__ e_sorted,
    float* __restrict__ out)
{
    const int wid = threadIdx.x >> 6;
    const int lane = threadIdx.x & 63;
    const int n = blockIdx.x * 4 + wid;
    if (n >= N_NODES) return;
    const int beg = offsets[n], end = offsets[n + 1];

    float m = -INFINITY;
    for (int j = beg + lane; j < end; j += 64) m = fmaxf(m, e_sorted[j]);
#pragma unroll
    for (int off = 32; off; off >>= 1) m = fmaxf(m, __shfl_down(m, off));
    m = __shfl(m, 0);

    float den = 0.f;
    for (int j = beg + lane; j < end; j += 64) den += expf(e_sorted[j] - m);
#pragma unroll
    for (int off = 32; off; off >>= 1) den += __shfl_down(den, off);
    den = __shfl(den, 0);
    float inv = (end > beg) ? 1.0f / den : 0.f;

    float4 acc = make_float4(0.f, 0.f, 0.f, 0.f);
    for (int j = beg; j < end; ++j) {
        float al = expf(e_sorted[j] - m) * inv;
        float4 zr = *(const float4*)&z[(size_t)src_sorted[j] * OUT_DIM + lane * 4];
        acc.x += al * zr.x;
        acc.y += al * zr.y;
        acc.z += al * zr.z;
        acc.w += al * zr.w;
    }
    *(float4*)&out[(size_t)n * OUT_DIM + lane * 4] = acc;
}

extern "C" void kernel_launch(void* const* d_in, const int* in_sizes, int n_in,
                              void* d_out, int out_size, void* d_ws, size_t ws_size,
                              hipStream_t stream) {
    const float* h      = (const float*)d_in[0];
    const float* fc_w   = (const float*)d_in[1];
    const float* fc_b   = (const float*)d_in[2];
    const float* attn_w = (const float*)d_in[3];
    const float* attn_b = (const float*)d_in[4];
    const int*   src    = (const int*)d_in[5];
    const int*   dst    = (const int*)d_in[6];
    float* out = (float*)d_out;

    // workspace carve-up
    float* z        = (float*)d_ws;                   // N_NODES*OUT_DIM
    float* s_src    = z + (size_t)N_NODES * OUT_DIM;  // N_NODES
    float* s_dst    = s_src + N_NODES;                // N_NODES
    float* e_arr    = s_dst + N_NODES;                // N_EDGES
    int*   deg      = (int*)(e_arr + N_EDGES);        // N_NODES
    int*   offsets  = deg + N_NODES;                  // N_NODES+1
    int*   cursor   = offsets + N_NODES + 1;          // N_NODES
    int*   src_sorted = cursor + N_NODES;             // N_EDGES
    float* e_sorted = (float*)(src_sorted + N_EDGES); // N_EDGES
    ushort* w_bf16  = (ushort*)(e_sorted + N_EDGES);  // OUT_DIM*IN_DIM

    // h_bf16 reuses d_out as scratch: 5.12M bf16 = 10.24 MB = out_size*4 exactly.
    ushort* h_bf16 = (ushort*)d_out;

    hipMemsetAsync(deg, 0, sizeof(int) * N_NODES, stream);
    hipMemsetAsync(cursor, 0, sizeof(int) * N_NODES, stream);

    f32_to_bf16<<<(N_NODES * IN_DIM / 8 + 255) / 256, 256, 0, stream>>>(h, h_bf16, N_NODES * IN_DIM / 8);
    f32_to_bf16<<<(OUT_DIM * IN_DIM / 8 + 255) / 256, 256, 0, stream>>>(fc_w, w_bf16, OUT_DIM * IN_DIM / 8);

    gemm_mfma<<<N_NODES / 16, 256, 0, stream>>>(h_bf16, w_bf16, fc_b, z);

    node_dots<<<(N_NODES + 3) / 4, 256, 0, stream>>>(z, attn_w, s_src, s_dst);

    edge_score<<<(N_EDGES + 255) / 256, 256, 0, stream>>>(src, dst, s_src, s_dst, attn_b, e_arr, deg);

    scan_deg<<<1, 1024, 0, stream>>>(deg, offsets);

    scatter_edges<<<(N_EDGES + 255) / 256, 256, 0, stream>>>(src, dst, e_arr, offsets, cursor, src_sorted, e_sorted);

    aggregate<<<(N_NODES + 3) / 4, 256, 0, stream>>>(z, offsets, src_sorted, e_sorted, out);
}

// Round 3
// 144.483 us; speedup vs baseline: 1.2476x; 1.0900x over previous
//
#include <hip/hip_runtime.h>
#include <hip/hip_bf16.h>
#include <math.h>

#define N_NODES 10000
#define N_EDGES 320000
#define IN_DIM  512
#define OUT_DIM 256
#define NEG_SLOPE 0.01f

typedef __attribute__((ext_vector_type(8))) short bf16x8;
typedef __attribute__((ext_vector_type(4))) float f32x4;

// ---------------- fp32 -> bf16 (RNE) convert, 8 elems/thread ----------------
__device__ __forceinline__ unsigned int f2bf(float x) {
    unsigned int b = __float_as_uint(x);
    return (b + 0x7fffu + ((b >> 16) & 1u)) >> 16;   // round-to-nearest-even
}

__global__ __launch_bounds__(256) void f32_to_bf16(
    const float* __restrict__ in, ushort* __restrict__ out, int n8)
{
    int i = blockIdx.x * 256 + threadIdx.x;
    if (i >= n8) return;
    const float* p = in + (size_t)i * 8;
    float4 v0 = *(const float4*)p;
    float4 v1 = *(const float4*)(p + 4);
    int4 o;
    o.x = (int)(f2bf(v0.x) | (f2bf(v0.y) << 16));
    o.y = (int)(f2bf(v0.z) | (f2bf(v0.w) << 16));
    o.z = (int)(f2bf(v1.x) | (f2bf(v1.y) << 16));
    o.w = (int)(f2bf(v1.z) | (f2bf(v1.w) << 16));
    *(int4*)(out + (size_t)i * 8) = o;
}

// ---------------- MFMA GEMM: z[M][N] = h[M][K] * fc_w[N][K]^T + fc_b --------
__global__ __launch_bounds__(256) void gemm_mfma(
    const ushort* __restrict__ A,   // h bf16 [M][K]
    const ushort* __restrict__ B,   // fc_w bf16 [N][K]
    const float* __restrict__ bias, // [N]
    float* __restrict__ C)          // z [M][N]
{
    const int K = IN_DIM;
    const int b = blockIdx.x;
    const int w = threadIdx.x >> 6;
    const int l = threadIdx.x & 63;
    const int lo = l & 15;
    const int hi = l >> 4;

    const int r0   = b * 16;        // 10000 = 625*16, exact
    const int colb = w * 64;

    const ushort* Arow = A + (size_t)(r0 + lo) * K;
    const ushort* B0 = B + (size_t)(colb + 0  + lo) * K;
    const ushort* B1 = B + (size_t)(colb + 16 + lo) * K;
    const ushort* B2 = B + (size_t)(colb + 32 + lo) * K;
    const ushort* B3 = B + (size_t)(colb + 48 + lo) * K;
    const int khalf = hi * 8;

    f32x4 acc0 = {0.f, 0.f, 0.f, 0.f};
    f32x4 acc1 = {0.f, 0.f, 0.f, 0.f};
    f32x4 acc2 = {0.f, 0.f, 0.f, 0.f};
    f32x4 acc3 = {0.f, 0.f, 0.f, 0.f};

#pragma unroll
    for (int ks = 0; ks < IN_DIM / 32; ++ks) {
        const int k = ks * 32 + khalf;
        bf16x8 a  = *(const bf16x8*)(Arow + k);
        bf16x8 b0 = *(const bf16x8*)(B0 + k);
        bf16x8 b1 = *(const bf16x8*)(B1 + k);
        bf16x8 b2 = *(const bf16x8*)(B2 + k);
        bf16x8 b3 = *(const bf16x8*)(B3 + k);
        acc0 = __builtin_amdgcn_mfma_f32_16x16x32_bf16(a, b0, acc0, 0, 0, 0);
        acc1 = __builtin_amdgcn_mfma_f32_16x16x32_bf16(a, b1, acc1, 0, 0, 0);
        acc2 = __builtin_amdgcn_mfma_f32_16x16x32_bf16(a, b2, acc2, 0, 0, 0);
        acc3 = __builtin_amdgcn_mfma_f32_16x16x32_bf16(a, b3, acc3, 0, 0, 0);
    }

    // C/D layout: col = lane&15, row = (lane>>4)*4 + i
    const float bv0 = bias[colb + 0  + lo];
    const float bv1 = bias[colb + 16 + lo];
    const float bv2 = bias[colb + 32 + lo];
    const float bv3 = bias[colb + 48 + lo];
#pragma unroll
    for (int i = 0; i < 4; ++i) {
        const int m = r0 + hi * 4 + i;
        float* cr = C + (size_t)m * OUT_DIM + colb + lo;
        cr[0]  = acc0[i] + bv0;
        cr[16] = acc1[i] + bv1;
        cr[32] = acc2[i] + bv2;
        cr[48] = acc3[i] + bv3;
    }
}

// ---------------- per-node attention dots ----------------
__global__ __launch_bounds__(256) void node_dots(
    const float* __restrict__ z, const float* __restrict__ attn_w,
    float* __restrict__ s_src, float* __restrict__ s_dst)
{
    const int wid = threadIdx.x >> 6;
    const int lane = threadIdx.x & 63;
    const int n = blockIdx.x * 4 + wid;
    if (n >= N_NODES) return;
    float4 zr = *(const float4*)&z[(size_t)n * OUT_DIM + lane * 4];
    float4 as = *(const float4*)&attn_w[lane * 4];
    float4 ad = *(const float4*)&attn_w[OUT_DIM + lane * 4];
    float dsv = zr.x * as.x + zr.y * as.y + zr.z * as.z + zr.w * as.w;
    float ddv = zr.x * ad.x + zr.y * ad.y + zr.z * ad.z + zr.w * ad.w;
#pragma unroll
    for (int off = 32; off; off >>= 1) {
        dsv += __shfl_down(dsv, off);
        ddv += __shfl_down(ddv, off);
    }
    if (lane == 0) { s_src[n] = dsv; s_dst[n] = ddv; }
}

// ---------------- dst histogram (int4-vectorized) ----------------
__global__ __launch_bounds__(256) void histogram(
    const int* __restrict__ dst, int* __restrict__ deg)
{
    int i = blockIdx.x * 256 + threadIdx.x;   // edge group of 4
    if (i >= N_EDGES / 4) return;
    int4 d = *(const int4*)&dst[i * 4];
    atomicAdd(&deg[d.x], 1);
    atomicAdd(&deg[d.y], 1);
    atomicAdd(&deg[d.z], 1);
    atomicAdd(&deg[d.w], 1);
}

// ---------------- fast single-block exclusive scan: 10 elems/thread --------
__global__ __launch_bounds__(1024) void scan_deg(
    const int* __restrict__ deg, int* __restrict__ offsets)
{
    const int t = threadIdx.x;
    const int lane = t & 63, wid = t >> 6;
    const int base = t * 10;

    int v[10];
    int tot = 0;
#pragma unroll
    for (int i = 0; i < 10; ++i) {
        int idx = base + i;
        v[i] = (idx < N_NODES) ? deg[idx] : 0;
        tot += v[i];
    }
    int sc = tot;
#pragma unroll
    for (int off = 1; off < 64; off <<= 1) {
        int u = __shfl_up(sc, off);
        if (lane >= off) sc += u;
    }
    __shared__ int wsum[16];
    if (lane == 63) wsum[wid] = sc;
    __syncthreads();
    int woff = 0;
    for (int ww = 0; ww < wid; ++ww) woff += wsum[ww];

    int run = woff + sc - tot;
    if (t == 0) offsets[0] = 0;
#pragma unroll
    for (int i = 0; i < 10; ++i) {
        int idx = base + i;
        run += v[i];
        if (idx < N_NODES) offsets[idx + 1] = run;
    }
}

// ---------------- fused score + scatter into CSR order ----------------
__global__ __launch_bounds__(256) void scatter_edges(
    const int* __restrict__ src, const int* __restrict__ dst,
    const float* __restrict__ s_src, const float* __restrict__ s_dst,
    const float* __restrict__ attn_b, const int* __restrict__ offsets,
    int* __restrict__ cursor, int* __restrict__ src_sorted,
    float* __restrict__ e_sorted)
{
    int k = blockIdx.x * 256 + threadIdx.x;
    if (k >= N_EDGES) return;
    int s = src[k], d = dst[k];
    float e = s_src[s] + s_dst[d] + attn_b[0];
    e = (e >= 0.f) ? e : NEG_SLOPE * e;
    int pos = offsets[d] + atomicAdd(&cursor[d], 1);
    src_sorted[pos] = s;
    e_sorted[pos] = e;
}

// ---------------- per-node softmax + weighted aggregation (wave/node) ------
// pass 3 unrolled x4: 4 independent 1KB gathers in flight per wave.
__global__ __launch_bounds__(256) void aggregate(
    const float* __restrict__ z, const int* __restrict__ offsets,
    const int* __restrict__ src_sorted, const float* __restrict__ e_sorted,
    float* __restrict__ out)
{
    const int wid = threadIdx.x >> 6;
    const int lane = threadIdx.x & 63;
    const int n = blockIdx.x * 4 + wid;
    if (n >= N_NODES) return;
    const int beg = offsets[n], end = offsets[n + 1];

    float m = -INFINITY;
    for (int j = beg + lane; j < end; j += 64) m = fmaxf(m, e_sorted[j]);
#pragma unroll
    for (int off = 32; off; off >>= 1) m = fmaxf(m, __shfl_xor(m, off));

    float den = 0.f;
    for (int j = beg + lane; j < end; j += 64) den += expf(e_sorted[j] - m);
#pragma unroll
    for (int off = 32; off; off >>= 1) den += __shfl_xor(den, off);
    float inv = (end > beg) ? 1.0f / den : 0.f;

    const int cidx = lane * 4;
    f32x4 a0 = {0.f,0.f,0.f,0.f}, a1 = {0.f,0.f,0.f,0.f};
    f32x4 a2 = {0.f,0.f,0.f,0.f}, a3 = {0.f,0.f,0.f,0.f};

    int j = beg;
    for (; j + 4 <= end; j += 4) {
        int s0 = src_sorted[j + 0];
        int s1 = src_sorted[j + 1];
        int s2 = src_sorted[j + 2];
        int s3 = src_sorted[j + 3];
        float w0 = expf(e_sorted[j + 0] - m) * inv;
        float w1 = expf(e_sorted[j + 1] - m) * inv;
        float w2 = expf(e_sorted[j + 2] - m) * inv;
        float w3 = expf(e_sorted[j + 3] - m) * inv;
        f32x4 z0 = *(const f32x4*)&z[(size_t)s0 * OUT_DIM + cidx];
        f32x4 z1 = *(const f32x4*)&z[(size_t)s1 * OUT_DIM + cidx];
        f32x4 z2 = *(const f32x4*)&z[(size_t)s2 * OUT_DIM + cidx];
        f32x4 z3 = *(const f32x4*)&z[(size_t)s3 * OUT_DIM + cidx];
        a0 += w0 * z0;
        a1 += w1 * z1;
        a2 += w2 * z2;
        a3 += w3 * z3;
    }
    for (; j < end; ++j) {
        int s0 = src_sorted[j];
        float w0 = expf(e_sorted[j] - m) * inv;
        f32x4 z0 = *(const f32x4*)&z[(size_t)s0 * OUT_DIM + cidx];
        a0 += w0 * z0;
    }
    f32x4 r = (a0 + a1) + (a2 + a3);
    *(f32x4*)&out[(size_t)n * OUT_DIM + cidx] = r;
}

extern "C" void kernel_launch(void* const* d_in, const int* in_sizes, int n_in,
                              void* d_out, int out_size, void* d_ws, size_t ws_size,
                              hipStream_t stream) {
    const float* h      = (const float*)d_in[0];
    const float* fc_w   = (const float*)d_in[1];
    const float* fc_b   = (const float*)d_in[2];
    const float* attn_w = (const float*)d_in[3];
    const float* attn_b = (const float*)d_in[4];
    const int*   src    = (const int*)d_in[5];
    const int*   dst    = (const int*)d_in[6];
    float* out = (float*)d_out;

    // workspace carve-up
    float* z        = (float*)d_ws;                   // N_NODES*OUT_DIM
    float* s_src    = z + (size_t)N_NODES * OUT_DIM;  // N_NODES
    float* s_dst    = s_src + N_NODES;                // N_NODES
    int*   deg      = (int*)(s_dst + N_NODES);        // N_NODES
    int*   offsets  = deg + N_NODES;                  // N_NODES+1
    int*   cursor   = offsets + N_NODES + 1;          // N_NODES
    int*   src_sorted = cursor + N_NODES + 3;         // N_EDGES (16B aligned)
    float* e_sorted = (float*)(src_sorted + N_EDGES); // N_EDGES
    ushort* w_bf16  = (ushort*)(e_sorted + N_EDGES);  // OUT_DIM*IN_DIM

    // h_bf16 reuses d_out as scratch: 5.12M bf16 = 10.24 MB = out_size*4 exactly.
    ushort* h_bf16 = (ushort*)d_out;

    hipMemsetAsync(deg, 0, sizeof(int) * N_NODES, stream);
    hipMemsetAsync(cursor, 0, sizeof(int) * N_NODES, stream);

    f32_to_bf16<<<(N_NODES * IN_DIM / 8 + 255) / 256, 256, 0, stream>>>(h, h_bf16, N_NODES * IN_DIM / 8);
    f32_to_bf16<<<(OUT_DIM * IN_DIM / 8 + 255) / 256, 256, 0, stream>>>(fc_w, w_bf16, OUT_DIM * IN_DIM / 8);

    gemm_mfma<<<N_NODES / 16, 256, 0, stream>>>(h_bf16, w_bf16, fc_b, z);

    node_dots<<<(N_NODES + 3) / 4, 256, 0, stream>>>(z, attn_w, s_src, s_dst);

    histogram<<<(N_EDGES / 4 + 255) / 256, 256, 0, stream>>>(dst, deg);

    scan_deg<<<1, 1024, 0, stream>>>(deg, offsets);

    scatter_edges<<<(N_EDGES + 255) / 256, 256, 0, stream>>>(src, dst, s_src, s_dst, attn_b, offsets, cursor, src_sorted, e_sorted);

    aggregate<<<(N_NODES + 3) / 4, 256, 0, stream>>>(z, offsets, src_sorted, e_sorted, out);
}

// Round 4
// 140.403 us; speedup vs baseline: 1.2839x; 1.0291x over previous
//
#include <hip/hip_runtime.h>
#include <hip/hip_bf16.h>
#include <math.h>

#define N_NODES 10000
#define N_EDGES 320000
#define IN_DIM  512
#define OUT_DIM 256
#define NEG_SLOPE 0.01f

typedef __attribute__((ext_vector_type(8))) short bf16x8;
typedef __attribute__((ext_vector_type(4))) float f32x4;

// ---------------- fp32 -> bf16 (RNE) convert, 8 elems/thread ----------------
__device__ __forceinline__ unsigned int f2bf(float x) {
    unsigned int b = __float_as_uint(x);
    return (b + 0x7fffu + ((b >> 16) & 1u)) >> 16;   // round-to-nearest-even
}

__global__ __launch_bounds__(256) void f32_to_bf16(
    const float* __restrict__ in, ushort* __restrict__ out, int n8)
{
    int i = blockIdx.x * 256 + threadIdx.x;
    if (i >= n8) return;
    const float* p = in + (size_t)i * 8;
    float4 v0 = *(const float4*)p;
    float4 v1 = *(const float4*)(p + 4);
    int4 o;
    o.x = (int)(f2bf(v0.x) | (f2bf(v0.y) << 16));
    o.y = (int)(f2bf(v0.z) | (f2bf(v0.w) << 16));
    o.z = (int)(f2bf(v1.x) | (f2bf(v1.y) << 16));
    o.w = (int)(f2bf(v1.z) | (f2bf(v1.w) << 16));
    *(int4*)(out + (size_t)i * 8) = o;
}

// ---------------- zero deg (replaces pathological graph-captured memset) ----
__global__ __launch_bounds__(256) void zero_deg(int* __restrict__ deg)
{
    int i = blockIdx.x * 256 + threadIdx.x;
    if (i < N_NODES) deg[i] = 0;
}

// ---------------- MFMA GEMM: z[M][N] = h[M][K] * fc_w[N][K]^T + fc_b --------
__global__ __launch_bounds__(256) void gemm_mfma(
    const ushort* __restrict__ A,   // h bf16 [M][K]
    const ushort* __restrict__ B,   // fc_w bf16 [N][K]
    const float* __restrict__ bias, // [N]
    float* __restrict__ C)          // z [M][N]
{
    const int K = IN_DIM;
    const int b = blockIdx.x;
    const int w = threadIdx.x >> 6;
    const int l = threadIdx.x & 63;
    const int lo = l & 15;
    const int hi = l >> 4;

    const int r0   = b * 16;        // 10000 = 625*16, exact
    const int colb = w * 64;

    const ushort* Arow = A + (size_t)(r0 + lo) * K;
    const ushort* B0 = B + (size_t)(colb + 0  + lo) * K;
    const ushort* B1 = B + (size_t)(colb + 16 + lo) * K;
    const ushort* B2 = B + (size_t)(colb + 32 + lo) * K;
    const ushort* B3 = B + (size_t)(colb + 48 + lo) * K;
    const int khalf = hi * 8;

    f32x4 acc0 = {0.f, 0.f, 0.f, 0.f};
    f32x4 acc1 = {0.f, 0.f, 0.f, 0.f};
    f32x4 acc2 = {0.f, 0.f, 0.f, 0.f};
    f32x4 acc3 = {0.f, 0.f, 0.f, 0.f};

#pragma unroll
    for (int ks = 0; ks < IN_DIM / 32; ++ks) {
        const int k = ks * 32 + khalf;
        bf16x8 a  = *(const bf16x8*)(Arow + k);
        bf16x8 b0 = *(const bf16x8*)(B0 + k);
        bf16x8 b1 = *(const bf16x8*)(B1 + k);
        bf16x8 b2 = *(const bf16x8*)(B2 + k);
        bf16x8 b3 = *(const bf16x8*)(B3 + k);
        acc0 = __builtin_amdgcn_mfma_f32_16x16x32_bf16(a, b0, acc0, 0, 0, 0);
        acc1 = __builtin_amdgcn_mfma_f32_16x16x32_bf16(a, b1, acc1, 0, 0, 0);
        acc2 = __builtin_amdgcn_mfma_f32_16x16x32_bf16(a, b2, acc2, 0, 0, 0);
        acc3 = __builtin_amdgcn_mfma_f32_16x16x32_bf16(a, b3, acc3, 0, 0, 0);
    }

    // C/D layout: col = lane&15, row = (lane>>4)*4 + i
    const float bv0 = bias[colb + 0  + lo];
    const float bv1 = bias[colb + 16 + lo];
    const float bv2 = bias[colb + 32 + lo];
    const float bv3 = bias[colb + 48 + lo];
#pragma unroll
    for (int i = 0; i < 4; ++i) {
        const int m = r0 + hi * 4 + i;
        float* cr = C + (size_t)m * OUT_DIM + colb + lo;
        cr[0]  = acc0[i] + bv0;
        cr[16] = acc1[i] + bv1;
        cr[32] = acc2[i] + bv2;
        cr[48] = acc3[i] + bv3;
    }
}

// ---------------- per-node attention dots ----------------
__global__ __launch_bounds__(256) void node_dots(
    const float* __restrict__ z, const float* __restrict__ attn_w,
    float* __restrict__ s_src, float* __restrict__ s_dst)
{
    const int wid = threadIdx.x >> 6;
    const int lane = threadIdx.x & 63;
    const int n = blockIdx.x * 4 + wid;
    if (n >= N_NODES) return;
    float4 zr = *(const float4*)&z[(size_t)n * OUT_DIM + lane * 4];
    float4 as = *(const float4*)&attn_w[lane * 4];
    float4 ad = *(const float4*)&attn_w[OUT_DIM + lane * 4];
    float dsv = zr.x * as.x + zr.y * as.y + zr.z * as.z + zr.w * as.w;
    float ddv = zr.x * ad.x + zr.y * ad.y + zr.z * ad.z + zr.w * ad.w;
#pragma unroll
    for (int off = 32; off; off >>= 1) {
        dsv += __shfl_down(dsv, off);
        ddv += __shfl_down(ddv, off);
    }
    if (lane == 0) { s_src[n] = dsv; s_dst[n] = ddv; }
}

// ---------------- dst histogram (int4-vectorized) ----------------
__global__ __launch_bounds__(256) void histogram(
    const int* __restrict__ dst, int* __restrict__ deg)
{
    int i = blockIdx.x * 256 + threadIdx.x;   // edge group of 4
    if (i >= N_EDGES / 4) return;
    int4 d = *(const int4*)&dst[i * 4];
    atomicAdd(&deg[d.x], 1);
    atomicAdd(&deg[d.y], 1);
    atomicAdd(&deg[d.z], 1);
    atomicAdd(&deg[d.w], 1);
}

// -------- single-block exclusive scan: 10/thread; writes offsets + cursor ---
__global__ __launch_bounds__(1024) void scan_deg(
    const int* __restrict__ deg, int* __restrict__ offsets,
    int* __restrict__ cursor)
{
    const int t = threadIdx.x;
    const int lane = t & 63, wid = t >> 6;
    const int base = t * 10;

    int v[10];
    int tot = 0;
#pragma unroll
    for (int i = 0; i < 10; ++i) {
        int idx = base + i;
        v[i] = (idx < N_NODES) ? deg[idx] : 0;
        tot += v[i];
    }
    int sc = tot;
#pragma unroll
    for (int off = 1; off < 64; off <<= 1) {
        int u = __shfl_up(sc, off);
        if (lane >= off) sc += u;
    }
    __shared__ int wsum[16];
    if (lane == 63) wsum[wid] = sc;
    __syncthreads();
    int woff = 0;
    for (int ww = 0; ww < wid; ++ww) woff += wsum[ww];

    int run = woff + sc - tot;     // exclusive prefix for this thread
    if (t == 0) offsets[0] = 0;
#pragma unroll
    for (int i = 0; i < 10; ++i) {
        int idx = base + i;
        if (idx < N_NODES) cursor[idx] = run;   // CSR start = scatter cursor init
        run += v[i];
        if (idx < N_NODES) offsets[idx + 1] = run;
    }
}

// ---------------- fused score + scatter into CSR order ----------------
__global__ __launch_bounds__(256) void scatter_edges(
    const int* __restrict__ src, const int* __restrict__ dst,
    const float* __restrict__ s_src, const float* __restrict__ s_dst,
    const float* __restrict__ attn_b,
    int* __restrict__ cursor, int* __restrict__ src_sorted,
    float* __restrict__ e_sorted)
{
    int k = blockIdx.x * 256 + threadIdx.x;
    if (k >= N_EDGES) return;
    int s = src[k], d = dst[k];
    float e = s_src[s] + s_dst[d] + attn_b[0];
    e = (e >= 0.f) ? e : NEG_SLOPE * e;
    int pos = atomicAdd(&cursor[d], 1);
    src_sorted[pos] = s;
    e_sorted[pos] = e;
}

// ---------------- per-node softmax + weighted aggregation (wave/node) ------
__global__ __launch_bounds__(256) void aggregate(
    const float* __restrict__ z, const int* __restrict__ offsets,
    const int* __restrict__ src_sorted, const float* __restrict__ e_sorted,
    float* __restrict__ out)
{
    const int wid = threadIdx.x >> 6;
    const int lane = threadIdx.x & 63;
    const int n = blockIdx.x * 4 + wid;
    if (n >= N_NODES) return;
    const int beg = offsets[n], end = offsets[n + 1];

    float m = -INFINITY;
    for (int j = beg + lane; j < end; j += 64) m = fmaxf(m, e_sorted[j]);
#pragma unroll
    for (int off = 32; off; off >>= 1) m = fmaxf(m, __shfl_xor(m, off));

    float den = 0.f;
    for (int j = beg + lane; j < end; j += 64) den += expf(e_sorted[j] - m);
#pragma unroll
    for (int off = 32; off; off >>= 1) den += __shfl_xor(den, off);
    float inv = (end > beg) ? 1.0f / den : 0.f;

    const int cidx = lane * 4;
    f32x4 a0 = {0.f,0.f,0.f,0.f}, a1 = {0.f,0.f,0.f,0.f};
    f32x4 a2 = {0.f,0.f,0.f,0.f}, a3 = {0.f,0.f,0.f,0.f};

    int j = beg;
    for (; j + 4 <= end; j += 4) {
        int s0 = src_sorted[j + 0];
        int s1 = src_sorted[j + 1];
        int s2 = src_sorted[j + 2];
        int s3 = src_sorted[j + 3];
        float w0 = expf(e_sorted[j + 0] - m) * inv;
        float w1 = expf(e_sorted[j + 1] - m) * inv;
        float w2 = expf(e_sorted[j + 2] - m) * inv;
        float w3 = expf(e_sorted[j + 3] - m) * inv;
        f32x4 z0 = *(const f32x4*)&z[(size_t)s0 * OUT_DIM + cidx];
        f32x4 z1 = *(const f32x4*)&z[(size_t)s1 * OUT_DIM + cidx];
        f32x4 z2 = *(const f32x4*)&z[(size_t)s2 * OUT_DIM + cidx];
        f32x4 z3 = *(const f32x4*)&z[(size_t)s3 * OUT_DIM + cidx];
        a0 += w0 * z0;
        a1 += w1 * z1;
        a2 += w2 * z2;
        a3 += w3 * z3;
    }
    for (; j < end; ++j) {
        int s0 = src_sorted[j];
        float w0 = expf(e_sorted[j] - m) * inv;
        f32x4 z0 = *(const f32x4*)&z[(size_t)s0 * OUT_DIM + cidx];
        a0 += w0 * z0;
    }
    f32x4 r = (a0 + a1) + (a2 + a3);
    *(f32x4*)&out[(size_t)n * OUT_DIM + cidx] = r;
}

extern "C" void kernel_launch(void* const* d_in, const int* in_sizes, int n_in,
                              void* d_out, int out_size, void* d_ws, size_t ws_size,
                              hipStream_t stream) {
    const float* h      = (const float*)d_in[0];
    const float* fc_w   = (const float*)d_in[1];
    const float* fc_b   = (const float*)d_in[2];
    const float* attn_w = (const float*)d_in[3];
    const float* attn_b = (const float*)d_in[4];
    const int*   src    = (const int*)d_in[5];
    const int*   dst    = (const int*)d_in[6];
    float* out = (float*)d_out;

    // workspace carve-up
    float* z        = (float*)d_ws;                   // N_NODES*OUT_DIM
    float* s_src    = z + (size_t)N_NODES * OUT_DIM;  // N_NODES
    float* s_dst    = s_src + N_NODES;                // N_NODES
    int*   deg      = (int*)(s_dst + N_NODES);        // N_NODES
    int*   offsets  = deg + N_NODES;                  // N_NODES+1
    int*   cursor   = offsets + N_NODES + 1;          // N_NODES
    int*   src_sorted = cursor + N_NODES + 3;         // N_EDGES (16B aligned)
    float* e_sorted = (float*)(src_sorted + N_EDGES); // N_EDGES
    ushort* w_bf16  = (ushort*)(e_sorted + N_EDGES);  // OUT_DIM*IN_DIM

    // h_bf16 reuses d_out as scratch: 5.12M bf16 = 10.24 MB = out_size*4 exactly.
    ushort* h_bf16 = (ushort*)d_out;

    zero_deg<<<(N_NODES + 255) / 256, 256, 0, stream>>>(deg);

    f32_to_bf16<<<(N_NODES * IN_DIM / 8 + 255) / 256, 256, 0, stream>>>(h, h_bf16, N_NODES * IN_DIM / 8);
    f32_to_bf16<<<(OUT_DIM * IN_DIM / 8 + 255) / 256, 256, 0, stream>>>(fc_w, w_bf16, OUT_DIM * IN_DIM / 8);

    gemm_mfma<<<N_NODES / 16, 256, 0, stream>>>(h_bf16, w_bf16, fc_b, z);

    node_dots<<<(N_NODES + 3) / 4, 256, 0, stream>>>(z, attn_w, s_src, s_dst);

    histogram<<<(N_EDGES / 4 + 255) / 256, 256, 0, stream>>>(dst, deg);

    scan_deg<<<1, 1024, 0, stream>>>(deg, offsets, cursor);

    scatter_edges<<<(N_EDGES + 255) / 256, 256, 0, stream>>>(src, dst, s_src, s_dst, attn_b, cursor, src_sorted, e_sorted);

    aggregate<<<(N_NODES + 3) / 4, 256, 0, stream>>>(z, offsets, src_sorted, e_sorted, out);
}

// Round 6
// 128.426 us; speedup vs baseline: 1.4036x; 1.0933x over previous
//
#include <hip/hip_runtime.h>
#include <hip/hip_bf16.h>
#include <math.h>

#define N_NODES 10000
#define N_EDGES 320000
#define IN_DIM  512
#define OUT_DIM 256
#define NEG_SLOPE 0.01f

typedef __attribute__((ext_vector_type(8))) short bf16x8;
typedef __attribute__((ext_vector_type(4))) float f32x4;

// ---------------- helpers ----------------
__device__ __forceinline__ unsigned int f2bf(float x) {
    unsigned int b = __float_as_uint(x);
    return (b + 0x7fffu + ((b >> 16) & 1u)) >> 16;   // round-to-nearest-even
}
__device__ __forceinline__ float bf2f(unsigned int u) {
    return __uint_as_float(u << 16);
}

// ---------------- prep: zero deg + convert fc_w to bf16 --------------------
// grid: 64 x 256 = 16384 threads; fc_w = 131072 elems = 16384 groups of 8.
__global__ __launch_bounds__(256) void prep(
    const float* __restrict__ fc_w, ushort* __restrict__ w_bf16,
    int* __restrict__ deg)
{
    int i = blockIdx.x * 256 + threadIdx.x;
    if (i < N_NODES) deg[i] = 0;
    const float* p = fc_w + (size_t)i * 8;
    float4 v0 = *(const float4*)p;
    float4 v1 = *(const float4*)(p + 4);
    int4 o;
    o.x = (int)(f2bf(v0.x) | (f2bf(v0.y) << 16));
    o.y = (int)(f2bf(v0.z) | (f2bf(v0.w) << 16));
    o.z = (int)(f2bf(v1.x) | (f2bf(v1.y) << 16));
    o.w = (int)(f2bf(v1.z) | (f2bf(v1.w) << 16));
    *(int4*)(w_bf16 + (size_t)i * 8) = o;
}

// ---------------- dst histogram (int4-vectorized) ----------------
__global__ __launch_bounds__(256) void histogram(
    const int* __restrict__ dst, int* __restrict__ deg)
{
    int i = blockIdx.x * 256 + threadIdx.x;   // edge group of 4
    if (i >= N_EDGES / 4) return;
    int4 d = *(const int4*)&dst[i * 4];
    atomicAdd(&deg[d.x], 1);
    atomicAdd(&deg[d.y], 1);
    atomicAdd(&deg[d.z], 1);
    atomicAdd(&deg[d.w], 1);
}

// ------ MFMA GEMM: z[M][N] = h[M][K] * fc_w[N][K]^T + fc_b, z stored bf16 --
// A read as f32 (read-once), converted to bf16 fragments in-register.
// block = 256 thr (4 waves) covers 16 rows x 256 cols.
__global__ __launch_bounds__(256) void gemm_mfma(
    const float* __restrict__ A,     // h f32 [M][K]
    const ushort* __restrict__ B,    // fc_w bf16 [N][K]
    const float* __restrict__ bias,  // [N]
    ushort* __restrict__ Zb)         // z bf16 [M][N]
{
    const int K = IN_DIM;
    const int b = blockIdx.x;
    const int w = threadIdx.x >> 6;
    const int l = threadIdx.x & 63;
    const int lo = l & 15;
    const int hi = l >> 4;

    const int r0   = b * 16;        // 10000 = 625*16, exact
    const int colb = w * 64;

    const float*  Arow = A + (size_t)(r0 + lo) * K;
    const ushort* B0 = B + (size_t)(colb + 0  + lo) * K;
    const ushort* B1 = B + (size_t)(colb + 16 + lo) * K;
    const ushort* B2 = B + (size_t)(colb + 32 + lo) * K;
    const ushort* B3 = B + (size_t)(colb + 48 + lo) * K;
    const int khalf = hi * 8;

    f32x4 acc0 = {0.f, 0.f, 0.f, 0.f};
    f32x4 acc1 = {0.f, 0.f, 0.f, 0.f};
    f32x4 acc2 = {0.f, 0.f, 0.f, 0.f};
    f32x4 acc3 = {0.f, 0.f, 0.f, 0.f};

#pragma unroll
    for (int ks = 0; ks < IN_DIM / 32; ++ks) {
        const int k = ks * 32 + khalf;
        float4 af0 = *(const float4*)(Arow + k);
        float4 af1 = *(const float4*)(Arow + k + 4);
        bf16x8 a;
        a[0] = (short)f2bf(af0.x);
        a[1] = (short)f2bf(af0.y);
        a[2] = (short)f2bf(af0.z);
        a[3] = (short)f2bf(af0.w);
        a[4] = (short)f2bf(af1.x);
        a[5] = (short)f2bf(af1.y);
        a[6] = (short)f2bf(af1.z);
        a[7] = (short)f2bf(af1.w);
        bf16x8 b0 = *(const bf16x8*)(B0 + k);
        bf16x8 b1 = *(const bf16x8*)(B1 + k);
        bf16x8 b2 = *(const bf16x8*)(B2 + k);
        bf16x8 b3 = *(const bf16x8*)(B3 + k);
        acc0 = __builtin_amdgcn_mfma_f32_16x16x32_bf16(a, b0, acc0, 0, 0, 0);
        acc1 = __builtin_amdgcn_mfma_f32_16x16x32_bf16(a, b1, acc1, 0, 0, 0);
        acc2 = __builtin_amdgcn_mfma_f32_16x16x32_bf16(a, b2, acc2, 0, 0, 0);
        acc3 = __builtin_amdgcn_mfma_f32_16x16x32_bf16(a, b3, acc3, 0, 0, 0);
    }

    // C/D layout: col = lane&15 (+16*cb), row = (lane>>4)*4 + i
    const int c0 = colb + lo;
    const float bv0 = bias[c0 + 0];
    const float bv1 = bias[c0 + 16];
    const float bv2 = bias[c0 + 32];
    const float bv3 = bias[c0 + 48];
#pragma unroll
    for (int i = 0; i < 4; ++i) {
        const int m = r0 + hi * 4 + i;
        ushort* zr = Zb + (size_t)m * OUT_DIM + c0;
        zr[0]  = (ushort)f2bf(acc0[i] + bv0);
        zr[16] = (ushort)f2bf(acc1[i] + bv1);
        zr[32] = (ushort)f2bf(acc2[i] + bv2);
        zr[48] = (ushort)f2bf(acc3[i] + bv3);
    }
}

// ---------------- per-node attention dots (bf16 z in, attn_b folded) -------
__global__ __launch_bounds__(256) void node_dots(
    const ushort* __restrict__ zb, const float* __restrict__ attn_w,
    const float* __restrict__ attn_b,
    float* __restrict__ s_src, float* __restrict__ s_dst)
{
    const int wid = threadIdx.x >> 6;
    const int lane = threadIdx.x & 63;
    const int n = blockIdx.x * 4 + wid;
    if (n >= N_NODES) return;
    ushort4 q = *(const ushort4*)&zb[(size_t)n * OUT_DIM + lane * 4];
    float4 as = *(const float4*)&attn_w[lane * 4];
    float4 ad = *(const float4*)&attn_w[OUT_DIM + lane * 4];
    float z0 = bf2f(q.x), z1 = bf2f(q.y), z2 = bf2f(q.z), z3 = bf2f(q.w);
    float dsv = z0 * as.x + z1 * as.y + z2 * as.z + z3 * as.w;
    float ddv = z0 * ad.x + z1 * ad.y + z2 * ad.z + z3 * ad.w;
#pragma unroll
    for (int off = 32; off; off >>= 1) {
        dsv += __shfl_xor(dsv, off);
        ddv += __shfl_xor(ddv, off);
    }
    if (lane == 0) { s_src[n] = dsv; s_dst[n] = ddv + attn_b[0]; }
}

// -------- single-block exclusive scan: 10/thread; writes offsets + cursor ---
__global__ __launch_bounds__(1024) void scan_deg(
    const int* __restrict__ deg, int* __restrict__ offsets,
    int* __restrict__ cursor)
{
    const int t = threadIdx.x;
    const int lane = t & 63, wid = t >> 6;
    const int base = t * 10;

    int v[10];
    int tot = 0;
#pragma unroll
    for (int i = 0; i < 10; ++i) {
        int idx = base + i;
        v[i] = (idx < N_NODES) ? deg[idx] : 0;
        tot += v[i];
    }
    int sc = tot;
#pragma unroll
    for (int off = 1; off < 64; off <<= 1) {
        int u = __shfl_up(sc, off);
        if (lane >= off) sc += u;
    }
    __shared__ int wsum[16];
    if (lane == 63) wsum[wid] = sc;
    __syncthreads();
    int woff = 0;
    for (int ww = 0; ww < wid; ++ww) woff += wsum[ww];

    int run = woff + sc - tot;     // exclusive prefix for this thread
    if (t == 0) offsets[0] = 0;
#pragma unroll
    for (int i = 0; i < 10; ++i) {
        int idx = base + i;
        if (idx < N_NODES) cursor[idx] = run;   // CSR start = scatter cursor init
        run += v[i];
        if (idx < N_NODES) offsets[idx + 1] = run;
    }
}

// -------- fused score + scatter into CSR order; 4 edges/thread, int2 recs ---
__global__ __launch_bounds__(256) void scatter_edges(
    const int* __restrict__ src, const int* __restrict__ dst,
    const float* __restrict__ s_src, const float* __restrict__ s_dst,
    int* __restrict__ cursor, int2* __restrict__ rec)
{
    int i = blockIdx.x * 256 + threadIdx.x;
    if (i >= N_EDGES / 4) return;
    int4 s4 = *(const int4*)&src[i * 4];
    int4 d4 = *(const int4*)&dst[i * 4];
#pragma unroll
    for (int u = 0; u < 4; ++u) {
        int s = (u == 0) ? s4.x : (u == 1) ? s4.y : (u == 2) ? s4.z : s4.w;
        int d = (u == 0) ? d4.x : (u == 1) ? d4.y : (u == 2) ? d4.z : d4.w;
        float e = s_src[s] + s_dst[d];            // attn_b folded into s_dst
        e = (e >= 0.f) ? e : NEG_SLOPE * e;
        int pos = atomicAdd(&cursor[d], 1);
        rec[pos] = make_int2(s, __float_as_int(e));
    }
}

// -------- per-node softmax + weighted aggregation (wave/node, bf16 gather) --
__global__ __launch_bounds__(256) void aggregate(
    const ushort* __restrict__ zb, const int* __restrict__ offsets,
    const int2* __restrict__ rec, float* __restrict__ out)
{
    const int wid = threadIdx.x >> 6;
    const int lane = threadIdx.x & 63;
    const int n = blockIdx.x * 4 + wid;
    if (n >= N_NODES) return;
    const int beg = offsets[n], end = offsets[n + 1];

    float m = -INFINITY;
    for (int j = beg + lane; j < end; j += 64) m = fmaxf(m, __int_as_float(rec[j].y));
#pragma unroll
    for (int off = 32; off; off >>= 1) m = fmaxf(m, __shfl_xor(m, off));

    float den = 0.f;
    for (int j = beg + lane; j < end; j += 64) den += expf(__int_as_float(rec[j].y) - m);
#pragma unroll
    for (int off = 32; off; off >>= 1) den += __shfl_xor(den, off);
    float inv = (end > beg) ? 1.0f / den : 0.f;

    const int cidx = lane * 4;
    f32x4 a0 = {0.f,0.f,0.f,0.f}, a1 = {0.f,0.f,0.f,0.f};
    f32x4 a2 = {0.f,0.f,0.f,0.f}, a3 = {0.f,0.f,0.f,0.f};

    int j = beg;
    for (; j + 4 <= end; j += 4) {
        int2 r0 = rec[j + 0];
        int2 r1 = rec[j + 1];
        int2 r2 = rec[j + 2];
        int2 r3 = rec[j + 3];
        float w0 = expf(__int_as_float(r0.y) - m) * inv;
        float w1 = expf(__int_as_float(r1.y) - m) * inv;
        float w2 = expf(__int_as_float(r2.y) - m) * inv;
        float w3 = expf(__int_as_float(r3.y) - m) * inv;
        ushort4 q0 = *(const ushort4*)&zb[(size_t)r0.x * OUT_DIM + cidx];
        ushort4 q1 = *(const ushort4*)&zb[(size_t)r1.x * OUT_DIM + cidx];
        ushort4 q2 = *(const ushort4*)&zb[(size_t)r2.x * OUT_DIM + cidx];
        ushort4 q3 = *(const ushort4*)&zb[(size_t)r3.x * OUT_DIM + cidx];
        f32x4 z0 = {bf2f(q0.x), bf2f(q0.y), bf2f(q0.z), bf2f(q0.w)};
        f32x4 z1 = {bf2f(q1.x), bf2f(q1.y), bf2f(q1.z), bf2f(q1.w)};
        f32x4 z2 = {bf2f(q2.x), bf2f(q2.y), bf2f(q2.z), bf2f(q2.w)};
        f32x4 z3 = {bf2f(q3.x), bf2f(q3.y), bf2f(q3.z), bf2f(q3.w)};
        a0 += w0 * z0;
        a1 += w1 * z1;
        a2 += w2 * z2;
        a3 += w3 * z3;
    }
    for (; j < end; ++j) {
        int2 r0 = rec[j];
        float w0 = expf(__int_as_float(r0.y) - m) * inv;
        ushort4 q0 = *(const ushort4*)&zb[(size_t)r0.x * OUT_DIM + cidx];
        f32x4 z0 = {bf2f(q0.x), bf2f(q0.y), bf2f(q0.z), bf2f(q0.w)};
        a0 += w0 * z0;
    }
    f32x4 r = (a0 + a1) + (a2 + a3);
    *(f32x4*)&out[(size_t)n * OUT_DIM + cidx] = r;
}

extern "C" void kernel_launch(void* const* d_in, const int* in_sizes, int n_in,
                              void* d_out, int out_size, void* d_ws, size_t ws_size,
                              hipStream_t stream) {
    const float* h      = (const float*)d_in[0];
    const float* fc_w   = (const float*)d_in[1];
    const float* fc_b   = (const float*)d_in[2];
    const float* attn_w = (const float*)d_in[3];
    const float* attn_b = (const float*)d_in[4];
    const int*   src    = (const int*)d_in[5];
    const int*   dst    = (const int*)d_in[6];
    float* out = (float*)d_out;

    // workspace carve-up (byte offsets all 16B-aligned)
    float* s_src   = (float*)d_ws;                    // 10000  @word 0
    float* s_dst   = s_src + N_NODES;                 // 10000  @word 10000
    int*   deg     = (int*)(s_dst + N_NODES);         // 10000  @word 20000
    int*   offsets = deg + N_NODES;                   // 10001  @word 30000
    int*   cursor  = offsets + N_NODES + 1;           // 10000  @word 40001
    int*   pad     = cursor + N_NODES;                // @word 50001, pad 3
    int2*  rec     = (int2*)(pad + 3);                // 320000 int2 @byte 200016
    ushort* z_bf16 = (ushort*)(rec + N_EDGES);        // 2.56M ushort @byte 2760016
    ushort* w_bf16 = z_bf16 + (size_t)N_NODES * OUT_DIM; // 131072 ushort

    prep<<<64, 256, 0, stream>>>(fc_w, w_bf16, deg);

    histogram<<<(N_EDGES / 4 + 255) / 256, 256, 0, stream>>>(dst, deg);

    gemm_mfma<<<N_NODES / 16, 256, 0, stream>>>(h, w_bf16, fc_b, z_bf16);

    node_dots<<<(N_NODES + 3) / 4, 256, 0, stream>>>(z_bf16, attn_w, attn_b, s_src, s_dst);

    scan_deg<<<1, 1024, 0, stream>>>(deg, offsets, cursor);

    scatter_edges<<<(N_EDGES / 4 + 255) / 256, 256, 0, stream>>>(src, dst, s_src, s_dst, cursor, rec);

    aggregate<<<(N_NODES + 3) / 4, 256, 0, stream>>>(z_bf16, offsets, rec, out);
}

// Round 7
// 126.404 us; speedup vs baseline: 1.4261x; 1.0160x over previous
//
#include <hip/hip_runtime.h>
#include <hip/hip_bf16.h>
#include <math.h>

#define N_NODES 10000
#define N_EDGES 320000
#define IN_DIM  512
#define OUT_DIM 256
#define NEG_SLOPE 0.01f

typedef __attribute__((ext_vector_type(8))) short bf16x8;
typedef __attribute__((ext_vector_type(4))) float f32x4;

// ---------------- helpers ----------------
__device__ __forceinline__ unsigned int f2bf(float x) {
    unsigned int b = __float_as_uint(x);
    return (b + 0x7fffu + ((b >> 16) & 1u)) >> 16;   // round-to-nearest-even
}
__device__ __forceinline__ float bf2f(unsigned int u) {
    return __uint_as_float(u << 16);
}

// ---------------- fp32 -> bf16 convert, 8 elems/thread ----------------
__global__ __launch_bounds__(256) void f32_to_bf16(
    const float* __restrict__ in, ushort* __restrict__ out, int n8)
{
    int i = blockIdx.x * 256 + threadIdx.x;
    if (i >= n8) return;
    const float* p = in + (size_t)i * 8;
    float4 v0 = *(const float4*)p;
    float4 v1 = *(const float4*)(p + 4);
    int4 o;
    o.x = (int)(f2bf(v0.x) | (f2bf(v0.y) << 16));
    o.y = (int)(f2bf(v0.z) | (f2bf(v0.w) << 16));
    o.z = (int)(f2bf(v1.x) | (f2bf(v1.y) << 16));
    o.w = (int)(f2bf(v1.z) | (f2bf(v1.w) << 16));
    *(int4*)(out + (size_t)i * 8) = o;
}

// ---------------- prep: zero deg + convert fc_w to bf16 --------------------
// grid: 64 x 256 = 16384 threads; fc_w = 131072 elems = 16384 groups of 8.
__global__ __launch_bounds__(256) void prep(
    const float* __restrict__ fc_w, ushort* __restrict__ w_bf16,
    int* __restrict__ deg)
{
    int i = blockIdx.x * 256 + threadIdx.x;
    if (i < N_NODES) deg[i] = 0;
    const float* p = fc_w + (size_t)i * 8;
    float4 v0 = *(const float4*)p;
    float4 v1 = *(const float4*)(p + 4);
    int4 o;
    o.x = (int)(f2bf(v0.x) | (f2bf(v0.y) << 16));
    o.y = (int)(f2bf(v0.z) | (f2bf(v0.w) << 16));
    o.z = (int)(f2bf(v1.x) | (f2bf(v1.y) << 16));
    o.w = (int)(f2bf(v1.z) | (f2bf(v1.w) << 16));
    *(int4*)(w_bf16 + (size_t)i * 8) = o;
}

// ---------------- dst histogram (int4-vectorized) ----------------
__global__ __launch_bounds__(256) void histogram(
    const int* __restrict__ dst, int* __restrict__ deg)
{
    int i = blockIdx.x * 256 + threadIdx.x;   // edge group of 4
    if (i >= N_EDGES / 4) return;
    int4 d = *(const int4*)&dst[i * 4];
    atomicAdd(&deg[d.x], 1);
    atomicAdd(&deg[d.y], 1);
    atomicAdd(&deg[d.z], 1);
    atomicAdd(&deg[d.w], 1);
}

// ------ MFMA GEMM: z[M][N] = h[M][K] * fc_w[N][K]^T + fc_b, z stored bf16 --
// grid (625, 2); block 256 = 4 waves. Block: 16 rows x 128 cols.
// Wave w: 16 rows x 32 cols (2 accumulators) -> 5000 waves (~4.9/SIMD).
// A-frag identical across the 4 waves of a block (L1 broadcast); B L2-resident.
__global__ __launch_bounds__(256) void gemm_mfma(
    const ushort* __restrict__ A,    // h bf16 [M][K]
    const ushort* __restrict__ B,    // fc_w bf16 [N][K]
    const float* __restrict__ bias,  // [N]
    ushort* __restrict__ Zb)         // z bf16 [M][N]
{
    const int K = IN_DIM;
    const int w = threadIdx.x >> 6;
    const int l = threadIdx.x & 63;
    const int lo = l & 15;
    const int hi = l >> 4;

    const int r0   = blockIdx.x * 16;              // 625 * 16 = 10000 exact
    const int colb = blockIdx.y * 128 + w * 32;    // 2 * 128 = 256 cols

    const ushort* Arow = A + (size_t)(r0 + lo) * K + hi * 8;
    const ushort* B0   = B + (size_t)(colb + 0  + lo) * K + hi * 8;
    const ushort* B1   = B + (size_t)(colb + 16 + lo) * K + hi * 8;

    f32x4 acc0 = {0.f, 0.f, 0.f, 0.f};
    f32x4 acc1 = {0.f, 0.f, 0.f, 0.f};

#pragma unroll
    for (int ks = 0; ks < IN_DIM / 32; ++ks) {
        bf16x8 a  = *(const bf16x8*)(Arow + ks * 32);
        bf16x8 b0 = *(const bf16x8*)(B0 + ks * 32);
        bf16x8 b1 = *(const bf16x8*)(B1 + ks * 32);
        acc0 = __builtin_amdgcn_mfma_f32_16x16x32_bf16(a, b0, acc0, 0, 0, 0);
        acc1 = __builtin_amdgcn_mfma_f32_16x16x32_bf16(a, b1, acc1, 0, 0, 0);
    }

    // C/D layout: col = lane&15 (+16*frag), row = (lane>>4)*4 + i
    const int c0 = colb + lo;
    const float bv0 = bias[c0 + 0];
    const float bv1 = bias[c0 + 16];
#pragma unroll
    for (int i = 0; i < 4; ++i) {
        const int m = r0 + hi * 4 + i;
        ushort* zr = Zb + (size_t)m * OUT_DIM + c0;
        zr[0]  = (ushort)f2bf(acc0[i] + bv0);
        zr[16] = (ushort)f2bf(acc1[i] + bv1);
    }
}

// ---------------- per-node attention dots (bf16 z in, attn_b folded) -------
__global__ __launch_bounds__(256) void node_dots(
    const ushort* __restrict__ zb, const float* __restrict__ attn_w,
    const float* __restrict__ attn_b,
    float* __restrict__ s_src, float* __restrict__ s_dst)
{
    const int wid = threadIdx.x >> 6;
    const int lane = threadIdx.x & 63;
    const int n = blockIdx.x * 4 + wid;
    if (n >= N_NODES) return;
    ushort4 q = *(const ushort4*)&zb[(size_t)n * OUT_DIM + lane * 4];
    float4 as = *(const float4*)&attn_w[lane * 4];
    float4 ad = *(const float4*)&attn_w[OUT_DIM + lane * 4];
    float z0 = bf2f(q.x), z1 = bf2f(q.y), z2 = bf2f(q.z), z3 = bf2f(q.w);
    float dsv = z0 * as.x + z1 * as.y + z2 * as.z + z3 * as.w;
    float ddv = z0 * ad.x + z1 * ad.y + z2 * ad.z + z3 * ad.w;
#pragma unroll
    for (int off = 32; off; off >>= 1) {
        dsv += __shfl_xor(dsv, off);
        ddv += __shfl_xor(ddv, off);
    }
    if (lane == 0) { s_src[n] = dsv; s_dst[n] = ddv + attn_b[0]; }
}

// -------- single-block exclusive scan: 10/thread; writes offsets + cursor ---
__global__ __launch_bounds__(1024) void scan_deg(
    const int* __restrict__ deg, int* __restrict__ offsets,
    int* __restrict__ cursor)
{
    const int t = threadIdx.x;
    const int lane = t & 63, wid = t >> 6;
    const int base = t * 10;

    int v[10];
    int tot = 0;
#pragma unroll
    for (int i = 0; i < 10; ++i) {
        int idx = base + i;
        v[i] = (idx < N_NODES) ? deg[idx] : 0;
        tot += v[i];
    }
    int sc = tot;
#pragma unroll
    for (int off = 1; off < 64; off <<= 1) {
        int u = __shfl_up(sc, off);
        if (lane >= off) sc += u;
    }
    __shared__ int wsum[16];
    if (lane == 63) wsum[wid] = sc;
    __syncthreads();
    int woff = 0;
    for (int ww = 0; ww < wid; ++ww) woff += wsum[ww];

    int run = woff + sc - tot;     // exclusive prefix for this thread
    if (t == 0) offsets[0] = 0;
#pragma unroll
    for (int i = 0; i < 10; ++i) {
        int idx = base + i;
        if (idx < N_NODES) cursor[idx] = run;   // CSR start = scatter cursor init
        run += v[i];
        if (idx < N_NODES) offsets[idx + 1] = run;
    }
}

// -------- fused score + scatter into CSR order; 4 edges/thread, int2 recs ---
__global__ __launch_bounds__(256) void scatter_edges(
    const int* __restrict__ src, const int* __restrict__ dst,
    const float* __restrict__ s_src, const float* __restrict__ s_dst,
    int* __restrict__ cursor, int2* __restrict__ rec)
{
    int i = blockIdx.x * 256 + threadIdx.x;
    if (i >= N_EDGES / 4) return;
    int4 s4 = *(const int4*)&src[i * 4];
    int4 d4 = *(const int4*)&dst[i * 4];
#pragma unroll
    for (int u = 0; u < 4; ++u) {
        int s = (u == 0) ? s4.x : (u == 1) ? s4.y : (u == 2) ? s4.z : s4.w;
        int d = (u == 0) ? d4.x : (u == 1) ? d4.y : (u == 2) ? d4.z : d4.w;
        float e = s_src[s] + s_dst[d];            // attn_b folded into s_dst
        e = (e >= 0.f) ? e : NEG_SLOPE * e;
        int pos = atomicAdd(&cursor[d], 1);
        rec[pos] = make_int2(s, __float_as_int(e));
    }
}

// -------- per-node softmax + weighted aggregation (wave/node, bf16 gather) --
__global__ __launch_bounds__(256) void aggregate(
    const ushort* __restrict__ zb, const int* __restrict__ offsets,
    const int2* __restrict__ rec, float* __restrict__ out)
{
    const int wid = threadIdx.x >> 6;
    const int lane = threadIdx.x & 63;
    const int n = blockIdx.x * 4 + wid;
    if (n >= N_NODES) return;
    const int beg = offsets[n], end = offsets[n + 1];

    float m = -INFINITY;
    for (int j = beg + lane; j < end; j += 64) m = fmaxf(m, __int_as_float(rec[j].y));
#pragma unroll
    for (int off = 32; off; off >>= 1) m = fmaxf(m, __shfl_xor(m, off));

    float den = 0.f;
    for (int j = beg + lane; j < end; j += 64) den += expf(__int_as_float(rec[j].y) - m);
#pragma unroll
    for (int off = 32; off; off >>= 1) den += __shfl_xor(den, off);
    float inv = (end > beg) ? 1.0f / den : 0.f;

    const int cidx = lane * 4;
    f32x4 a0 = {0.f,0.f,0.f,0.f}, a1 = {0.f,0.f,0.f,0.f};
    f32x4 a2 = {0.f,0.f,0.f,0.f}, a3 = {0.f,0.f,0.f,0.f};

    int j = beg;
    for (; j + 4 <= end; j += 4) {
        int2 r0 = rec[j + 0];
        int2 r1 = rec[j + 1];
        int2 r2 = rec[j + 2];
        int2 r3 = rec[j + 3];
        float w0 = expf(__int_as_float(r0.y) - m) * inv;
        float w1 = expf(__int_as_float(r1.y) - m) * inv;
        float w2 = expf(__int_as_float(r2.y) - m) * inv;
        float w3 = expf(__int_as_float(r3.y) - m) * inv;
        ushort4 q0 = *(const ushort4*)&zb[(size_t)r0.x * OUT_DIM + cidx];
        ushort4 q1 = *(const ushort4*)&zb[(size_t)r1.x * OUT_DIM + cidx];
        ushort4 q2 = *(const ushort4*)&zb[(size_t)r2.x * OUT_DIM + cidx];
        ushort4 q3 = *(const ushort4*)&zb[(size_t)r3.x * OUT_DIM + cidx];
        f32x4 z0 = {bf2f(q0.x), bf2f(q0.y), bf2f(q0.z), bf2f(q0.w)};
        f32x4 z1 = {bf2f(q1.x), bf2f(q1.y), bf2f(q1.z), bf2f(q1.w)};
        f32x4 z2 = {bf2f(q2.x), bf2f(q2.y), bf2f(q2.z), bf2f(q2.w)};
        f32x4 z3 = {bf2f(q3.x), bf2f(q3.y), bf2f(q3.z), bf2f(q3.w)};
        a0 += w0 * z0;
        a1 += w1 * z1;
        a2 += w2 * z2;
        a3 += w3 * z3;
    }
    for (; j < end; ++j) {
        int2 r0 = rec[j];
        float w0 = expf(__int_as_float(r0.y) - m) * inv;
        ushort4 q0 = *(const ushort4*)&zb[(size_t)r0.x * OUT_DIM + cidx];
        f32x4 z0 = {bf2f(q0.x), bf2f(q0.y), bf2f(q0.z), bf2f(q0.w)};
        a0 += w0 * z0;
    }
    f32x4 r = (a0 + a1) + (a2 + a3);
    *(f32x4*)&out[(size_t)n * OUT_DIM + cidx] = r;
}

extern "C" void kernel_launch(void* const* d_in, const int* in_sizes, int n_in,
                              void* d_out, int out_size, void* d_ws, size_t ws_size,
                              hipStream_t stream) {
    const float* h      = (const float*)d_in[0];
    const float* fc_w   = (const float*)d_in[1];
    const float* fc_b   = (const float*)d_in[2];
    const float* attn_w = (const float*)d_in[3];
    const float* attn_b = (const float*)d_in[4];
    const int*   src    = (const int*)d_in[5];
    const int*   dst    = (const int*)d_in[6];
    float* out = (float*)d_out;

    // workspace carve-up (all 16B-aligned)
    float* s_src   = (float*)d_ws;                    // 10000  @word 0
    float* s_dst   = s_src + N_NODES;                 // 10000  @word 10000
    int*   deg     = (int*)(s_dst + N_NODES);         // 10000  @word 20000
    int*   offsets = deg + N_NODES;                   // 10001  @word 30000
    int*   cursor  = offsets + N_NODES + 1;           // 10000  @word 40001
    int*   pad     = cursor + N_NODES;                // @word 50001, pad 3
    int2*  rec     = (int2*)(pad + 3);                // 320000 int2 @byte 200016
    ushort* z_bf16 = (ushort*)(rec + N_EDGES);        // 2.56M ushort @byte 2760016
    ushort* w_bf16 = z_bf16 + (size_t)N_NODES * OUT_DIM; // 131072 ushort
    ushort* h_bf16 = w_bf16 + (size_t)OUT_DIM * IN_DIM;  // 5.12M ushort (10.24MB)

    prep<<<64, 256, 0, stream>>>(fc_w, w_bf16, deg);

    f32_to_bf16<<<(N_NODES * IN_DIM / 8 + 255) / 256, 256, 0, stream>>>(h, h_bf16, N_NODES * IN_DIM / 8);

    histogram<<<(N_EDGES / 4 + 255) / 256, 256, 0, stream>>>(dst, deg);

    gemm_mfma<<<dim3(N_NODES / 16, 2), 256, 0, stream>>>(h_bf16, w_bf16, fc_b, z_bf16);

    node_dots<<<(N_NODES + 3) / 4, 256, 0, stream>>>(z_bf16, attn_w, attn_b, s_src, s_dst);

    scan_deg<<<1, 1024, 0, stream>>>(deg, offsets, cursor);

    scatter_edges<<<(N_EDGES / 4 + 255) / 256, 256, 0, stream>>>(src, dst, s_src, s_dst, cursor, rec);

    aggregate<<<(N_NODES + 3) / 4, 256, 0, stream>>>(z_bf16, offsets, rec, out);
}

// Round 8
// 115.070 us; speedup vs baseline: 1.5665x; 1.0985x over previous
//
#include <hip/hip_runtime.h>
#include <hip/hip_bf16.h>
#include <math.h>

#define N_NODES 10000
#define N_EDGES 320000
#define IN_DIM  512
#define OUT_DIM 256
#define NEG_SLOPE 0.01f

typedef __attribute__((ext_vector_type(8))) short bf16x8;
typedef __attribute__((ext_vector_type(4))) float f32x4;

// ---------------- helpers ----------------
__device__ __forceinline__ unsigned int f2bf(float x) {
    unsigned int b = __float_as_uint(x);
    return (b + 0x7fffu + ((b >> 16) & 1u)) >> 16;   // round-to-nearest-even
}
__device__ __forceinline__ float bf2f(unsigned int u) {
    return __uint_as_float(u << 16);
}

// ---------- K1: fused {convert h, convert fc_w, zero deg} ----------
// blocks 0..2499   : h groups  (2500*256 = 640000 groups of 8 = 5.12M)
// blocks 2500..2563: fc_w groups (64*256 = 16384 groups of 8 = 131072)
// blocks 2564..2603: zero deg (40*256 >= 10000)
__global__ __launch_bounds__(256) void setup(
    const float* __restrict__ h, const float* __restrict__ fc_w,
    ushort* __restrict__ h_bf16, ushort* __restrict__ w_bf16,
    int* __restrict__ deg)
{
    const int b = blockIdx.x;
    const int t = threadIdx.x;
    if (b < 2500) {
        int i = b * 256 + t;
        const float* p = h + (size_t)i * 8;
        float4 v0 = *(const float4*)p;
        float4 v1 = *(const float4*)(p + 4);
        int4 o;
        o.x = (int)(f2bf(v0.x) | (f2bf(v0.y) << 16));
        o.y = (int)(f2bf(v0.z) | (f2bf(v0.w) << 16));
        o.z = (int)(f2bf(v1.x) | (f2bf(v1.y) << 16));
        o.w = (int)(f2bf(v1.z) | (f2bf(v1.w) << 16));
        *(int4*)(h_bf16 + (size_t)i * 8) = o;
    } else if (b < 2564) {
        int i = (b - 2500) * 256 + t;
        const float* p = fc_w + (size_t)i * 8;
        float4 v0 = *(const float4*)p;
        float4 v1 = *(const float4*)(p + 4);
        int4 o;
        o.x = (int)(f2bf(v0.x) | (f2bf(v0.y) << 16));
        o.y = (int)(f2bf(v0.z) | (f2bf(v0.w) << 16));
        o.z = (int)(f2bf(v1.x) | (f2bf(v1.y) << 16));
        o.w = (int)(f2bf(v1.z) | (f2bf(v1.w) << 16));
        *(int4*)(w_bf16 + (size_t)i * 8) = o;
    } else {
        int i = (b - 2564) * 256 + t;
        if (i < N_NODES) deg[i] = 0;
    }
}

// ------ K2: MFMA GEMM: z = h * fc_w^T + b, z stored bf16 ------
// grid (625, 2); block 256 = 4 waves. Wave: 16 rows x 32 cols, 2 accumulators.
__global__ __launch_bounds__(256) void gemm_mfma(
    const ushort* __restrict__ A,    // h bf16 [M][K]
    const ushort* __restrict__ B,    // fc_w bf16 [N][K]
    const float* __restrict__ bias,  // [N]
    ushort* __restrict__ Zb)         // z bf16 [M][N]
{
    const int K = IN_DIM;
    const int w = threadIdx.x >> 6;
    const int l = threadIdx.x & 63;
    const int lo = l & 15;
    const int hi = l >> 4;

    const int r0   = blockIdx.x * 16;              // 625 * 16 = 10000 exact
    const int colb = blockIdx.y * 128 + w * 32;    // 2 * 128 = 256 cols

    const ushort* Arow = A + (size_t)(r0 + lo) * K + hi * 8;
    const ushort* B0   = B + (size_t)(colb + 0  + lo) * K + hi * 8;
    const ushort* B1   = B + (size_t)(colb + 16 + lo) * K + hi * 8;

    f32x4 acc0 = {0.f, 0.f, 0.f, 0.f};
    f32x4 acc1 = {0.f, 0.f, 0.f, 0.f};

#pragma unroll
    for (int ks = 0; ks < IN_DIM / 32; ++ks) {
        bf16x8 a  = *(const bf16x8*)(Arow + ks * 32);
        bf16x8 b0 = *(const bf16x8*)(B0 + ks * 32);
        bf16x8 b1 = *(const bf16x8*)(B1 + ks * 32);
        acc0 = __builtin_amdgcn_mfma_f32_16x16x32_bf16(a, b0, acc0, 0, 0, 0);
        acc1 = __builtin_amdgcn_mfma_f32_16x16x32_bf16(a, b1, acc1, 0, 0, 0);
    }

    // C/D layout: col = lane&15 (+16*frag), row = (lane>>4)*4 + i
    const int c0 = colb + lo;
    const float bv0 = bias[c0 + 0];
    const float bv1 = bias[c0 + 16];
#pragma unroll
    for (int i = 0; i < 4; ++i) {
        const int m = r0 + hi * 4 + i;
        ushort* zr = Zb + (size_t)m * OUT_DIM + c0;
        zr[0]  = (ushort)f2bf(acc0[i] + bv0);
        zr[16] = (ushort)f2bf(acc1[i] + bv1);
    }
}

// ---------- K3: fused {dst histogram, node attention dots} ----------
// blocks 0..312    : histogram (313*256*4 >= 320000 edges)
// blocks 313..2812 : node_dots (2500*4 = 10000 nodes, 1 wave/node)
#define HIST_BLOCKS 313
__global__ __launch_bounds__(256) void hist_dots(
    const int* __restrict__ dst, int* __restrict__ deg,
    const ushort* __restrict__ zb, const float* __restrict__ attn_w,
    const float* __restrict__ attn_b,
    float* __restrict__ s_src, float* __restrict__ s_dst)
{
    const int b = blockIdx.x;
    if (b < HIST_BLOCKS) {
        int i = b * 256 + threadIdx.x;   // edge group of 4
        if (i >= N_EDGES / 4) return;
        int4 d = *(const int4*)&dst[i * 4];
        atomicAdd(&deg[d.x], 1);
        atomicAdd(&deg[d.y], 1);
        atomicAdd(&deg[d.z], 1);
        atomicAdd(&deg[d.w], 1);
    } else {
        const int wid = threadIdx.x >> 6;
        const int lane = threadIdx.x & 63;
        const int n = (b - HIST_BLOCKS) * 4 + wid;
        if (n >= N_NODES) return;
        ushort4 q = *(const ushort4*)&zb[(size_t)n * OUT_DIM + lane * 4];
        float4 as = *(const float4*)&attn_w[lane * 4];
        float4 ad = *(const float4*)&attn_w[OUT_DIM + lane * 4];
        float z0 = bf2f(q.x), z1 = bf2f(q.y), z2 = bf2f(q.z), z3 = bf2f(q.w);
        float dsv = z0 * as.x + z1 * as.y + z2 * as.z + z3 * as.w;
        float ddv = z0 * ad.x + z1 * ad.y + z2 * ad.z + z3 * ad.w;
#pragma unroll
        for (int off = 32; off; off >>= 1) {
            dsv += __shfl_xor(dsv, off);
            ddv += __shfl_xor(ddv, off);
        }
        if (lane == 0) { s_src[n] = dsv; s_dst[n] = ddv + attn_b[0]; }
    }
}

// -------- K4: single-block exclusive scan: 10/thread; offsets + cursor ------
__global__ __launch_bounds__(1024) void scan_deg(
    const int* __restrict__ deg, int* __restrict__ offsets,
    int* __restrict__ cursor)
{
    const int t = threadIdx.x;
    const int lane = t & 63, wid = t >> 6;
    const int base = t * 10;

    int v[10];
    int tot = 0;
#pragma unroll
    for (int i = 0; i < 10; ++i) {
        int idx = base + i;
        v[i] = (idx < N_NODES) ? deg[idx] : 0;
        tot += v[i];
    }
    int sc = tot;
#pragma unroll
    for (int off = 1; off < 64; off <<= 1) {
        int u = __shfl_up(sc, off);
        if (lane >= off) sc += u;
    }
    __shared__ int wsum[16];
    if (lane == 63) wsum[wid] = sc;
    __syncthreads();
    int woff = 0;
    for (int ww = 0; ww < wid; ++ww) woff += wsum[ww];

    int run = woff + sc - tot;     // exclusive prefix for this thread
    if (t == 0) offsets[0] = 0;
#pragma unroll
    for (int i = 0; i < 10; ++i) {
        int idx = base + i;
        if (idx < N_NODES) cursor[idx] = run;   // CSR start = scatter cursor init
        run += v[i];
        if (idx < N_NODES) offsets[idx + 1] = run;
    }
}

// -------- K5: fused score + scatter into CSR order; 4 edges/thread ----------
__global__ __launch_bounds__(256) void scatter_edges(
    const int* __restrict__ src, const int* __restrict__ dst,
    const float* __restrict__ s_src, const float* __restrict__ s_dst,
    int* __restrict__ cursor, int2* __restrict__ rec)
{
    int i = blockIdx.x * 256 + threadIdx.x;
    if (i >= N_EDGES / 4) return;
    int4 s4 = *(const int4*)&src[i * 4];
    int4 d4 = *(const int4*)&dst[i * 4];
#pragma unroll
    for (int u = 0; u < 4; ++u) {
        int s = (u == 0) ? s4.x : (u == 1) ? s4.y : (u == 2) ? s4.z : s4.w;
        int d = (u == 0) ? d4.x : (u == 1) ? d4.y : (u == 2) ? d4.z : d4.w;
        float e = s_src[s] + s_dst[d];            // attn_b folded into s_dst
        e = (e >= 0.f) ? e : NEG_SLOPE * e;
        int pos = atomicAdd(&cursor[d], 1);
        rec[pos] = make_int2(s, __float_as_int(e));
    }
}

// -------- K6: softmax + weighted aggregation; 2 edges per wave-step ---------
// Wave = one node. Lanes split into halves; half p handles edge (j+p),
// each lane gathers 16B (8 cols) of its edge's z-row. 8 edges in flight.
__global__ __launch_bounds__(256) void aggregate(
    const ushort* __restrict__ zb, const int* __restrict__ offsets,
    const int2* __restrict__ rec, float* __restrict__ out)
{
    const int wid = threadIdx.x >> 6;
    const int lane = threadIdx.x & 63;
    const int half = lane >> 5;
    const int sl = lane & 31;
    const int n = blockIdx.x * 4 + wid;
    if (n >= N_NODES) return;
    const int beg = offsets[n], end = offsets[n + 1];

    float m = -INFINITY;
    for (int j = beg + lane; j < end; j += 64) m = fmaxf(m, __int_as_float(rec[j].y));
#pragma unroll
    for (int off = 32; off; off >>= 1) m = fmaxf(m, __shfl_xor(m, off));

    float den = 0.f;
    for (int j = beg + lane; j < end; j += 64) den += expf(__int_as_float(rec[j].y) - m);
#pragma unroll
    for (int off = 32; off; off >>= 1) den += __shfl_xor(den, off);
    float inv = (end > beg) ? 1.0f / den : 0.f;

    const int cbase = sl * 8;
    float acc[8] = {0.f, 0.f, 0.f, 0.f, 0.f, 0.f, 0.f, 0.f};

    int j = beg;
    for (; j + 8 <= end; j += 8) {
#pragma unroll
        for (int u = 0; u < 4; ++u) {
            int2 r = rec[j + 2 * u + half];
            float wgt = expf(__int_as_float(r.y) - m) * inv;
            bf16x8 q = *(const bf16x8*)&zb[(size_t)r.x * OUT_DIM + cbase];
#pragma unroll
            for (int c = 0; c < 8; ++c)
                acc[c] += wgt * bf2f((unsigned short)q[c]);
        }
    }
    for (; j < end; j += 2) {
        if (j + half < end) {
            int2 r = rec[j + half];
            float wgt = expf(__int_as_float(r.y) - m) * inv;
            bf16x8 q = *(const bf16x8*)&zb[(size_t)r.x * OUT_DIM + cbase];
#pragma unroll
            for (int c = 0; c < 8; ++c)
                acc[c] += wgt * bf2f((unsigned short)q[c]);
        }
    }
    // merge the two halves; then each lane stores 16B of the final row
#pragma unroll
    for (int c = 0; c < 8; ++c) acc[c] += __shfl_xor(acc[c], 32);
    f32x4 st;
    st[0] = acc[half * 4 + 0];
    st[1] = acc[half * 4 + 1];
    st[2] = acc[half * 4 + 2];
    st[3] = acc[half * 4 + 3];
    *(f32x4*)&out[(size_t)n * OUT_DIM + cbase + half * 4] = st;
}

extern "C" void kernel_launch(void* const* d_in, const int* in_sizes, int n_in,
                              void* d_out, int out_size, void* d_ws, size_t ws_size,
                              hipStream_t stream) {
    const float* h      = (const float*)d_in[0];
    const float* fc_w   = (const float*)d_in[1];
    const float* fc_b   = (const float*)d_in[2];
    const float* attn_w = (const float*)d_in[3];
    const float* attn_b = (const float*)d_in[4];
    const int*   src    = (const int*)d_in[5];
    const int*   dst    = (const int*)d_in[6];
    float* out = (float*)d_out;

    // workspace carve-up (all 16B-aligned)
    float* s_src   = (float*)d_ws;                    // 10000  @word 0
    float* s_dst   = s_src + N_NODES;                 // 10000  @word 10000
    int*   deg     = (int*)(s_dst + N_NODES);         // 10000  @word 20000
    int*   offsets = deg + N_NODES;                   // 10001  @word 30000
    int*   cursor  = offsets + N_NODES + 1;           // 10000  @word 40001
    int*   pad     = cursor + N_NODES;                // @word 50001, pad 3
    int2*  rec     = (int2*)(pad + 3);                // 320000 int2
    ushort* z_bf16 = (ushort*)(rec + N_EDGES);        // 2.56M ushort
    ushort* w_bf16 = z_bf16 + (size_t)N_NODES * OUT_DIM; // 131072 ushort
    ushort* h_bf16 = w_bf16 + (size_t)OUT_DIM * IN_DIM;  // 5.12M ushort

    setup<<<2604, 256, 0, stream>>>(h, fc_w, h_bf16, w_bf16, deg);

    gemm_mfma<<<dim3(N_NODES / 16, 2), 256, 0, stream>>>(h_bf16, w_bf16, fc_b, z_bf16);

    hist_dots<<<HIST_BLOCKS + 2500, 256, 0, stream>>>(dst, deg, z_bf16, attn_w, attn_b, s_src, s_dst);

    scan_deg<<<1, 1024, 0, stream>>>(deg, offsets, cursor);

    scatter_edges<<<(N_EDGES / 4 + 255) / 256, 256, 0, stream>>>(src, dst, s_src, s_dst, cursor, rec);

    aggregate<<<(N_NODES + 3) / 4, 256, 0, stream>>>(z_bf16, offsets, rec, out);
}